// Round 9
// baseline (520.190 us; speedup 1.0000x reference)
//
#include <hip/hip_runtime.h>
#include <math.h>

// ---------------------------------------------------------------------------
// MLPEncoder (NRI encoder) on MI355X — round 22: mlp4 GEMM remap col-split ->
// 2x4 wave grid (wave owns 64 rows x 64 cols of the 128-row tile).
// Rationale: GEMM phases are LDS-read-bound — col-split makes every wave
// read the full 128x256 A-tile (512 KB/block/GEMM); 2x4 halves A-reads
// (32 ds_read_b128/wave) at the cost of 2x W-fragment loads (L2-resident).
// acc[4][4] = same 64 AGPR; wf0[4]+wf1[4]+af keeps VGPR side ~60 (<=64).
// mlp2 unchanged (e2n tail needs cross-wave combine under 2x4 — next round).
// ---------------------------------------------------------------------------

typedef unsigned short ushort_t;
typedef __bf16 bf16x8 __attribute__((ext_vector_type(8)));
typedef float  f32x4  __attribute__((ext_vector_type(4)));

#define E_EDGES 9900
#define NNODE   100
#define HID     256
#define M_BIG   316800
#define M_SMALL 3200
#define NBLK2   (M_BIG / 128)   /* 2475 */

__device__ __forceinline__ float bf2f(ushort_t u) {
    union { unsigned int i; float f; } v; v.i = ((unsigned int)u) << 16; return v.f;
}
__device__ __forceinline__ ushort_t f2bf(float f) {
    union { __bf16 h; ushort_t u; } v; v.h = (__bf16)f; return v.u;   // RNE
}
__device__ __forceinline__ float elu_f(float x) {
    return x > 0.f ? x : (__expf(x) - 1.f);
}

// ---- convert all weights to chan-major bf16 WT[col][K] --------------------
__global__ __launch_bounds__(256)
void wcvt_all(const float* __restrict__ s0, const float* __restrict__ s1,
              const float* __restrict__ s2, const float* __restrict__ s3,
              const float* __restrict__ s4, const float* __restrict__ s5,
              const float* __restrict__ s6, const float* __restrict__ s7,
              ushort_t* d0, ushort_t* d1, ushort_t* d2, ushort_t* d3,
              ushort_t* d4, ushort_t* d5, ushort_t* d6, ushort_t* d7)
{
    int bid = blockIdx.x;
    const float* S; ushort_t* D; int Kd, Kr, t;
    if      (bid < 16)  { S = s0; D = d0; Kd = 256; Kr = 200; t = bid; }
    else if (bid < 32)  { S = s1; D = d1; Kd = 256; Kr = 256; t = bid - 16; }
    else if (bid < 64)  { S = s2; D = d2; Kd = 512; Kr = 512; t = bid - 32; }
    else if (bid < 80)  { S = s3; D = d3; Kd = 256; Kr = 256; t = bid - 64; }
    else if (bid < 96)  { S = s4; D = d4; Kd = 256; Kr = 256; t = bid - 80; }
    else if (bid < 112) { S = s5; D = d5; Kd = 256; Kr = 256; t = bid - 96; }
    else if (bid < 160) { S = s6; D = d6; Kd = 768; Kr = 768; t = bid - 112; }
    else                { S = s7; D = d7; Kd = 256; Kr = 256; t = bid - 160; }
    int k0 = (t >> 2) * 64, c0 = (t & 3) * 64;
    __shared__ float Sh[64][65];
    int tid = threadIdx.x;
    #pragma unroll
    for (int i = 0; i < 16; ++i) {
        int idx = tid + i * 256;
        int kk = idx >> 6, cc = idx & 63;
        Sh[kk][cc] = (k0 + kk < Kr) ? S[(size_t)(k0 + kk) * 256 + c0 + cc] : 0.f;
    }
    __syncthreads();
    int col = tid & 63;
    int kb  = (tid >> 6) * 16;
    ushort_t* dst = D + (size_t)(c0 + col) * Kd + k0 + kb;
    #pragma unroll
    for (int jj = 0; jj < 4; ++jj) {
        ushort4 u;
        u.x = f2bf(Sh[kb + 4 * jj + 0][col]);
        u.y = f2bf(Sh[kb + 4 * jj + 1][col]);
        u.z = f2bf(Sh[kb + 4 * jj + 2][col]);
        u.w = f2bf(Sh[kb + 4 * jj + 3][col]);
        *(ushort4*)(dst + 4 * jj) = u;
    }
}

// ---- 2-row-tile GEMM helper over a 32x264 LDS tile (small chain) ----------
__device__ __forceinline__ void gemm32(const ushort_t S[32][264],
                                       const ushort_t* __restrict__ WT,
                                       int wstr, int kcn,
                                       int w, int ln15, int klane,
                                       f32x4 acc[2][4])
{
    #pragma unroll
    for (int r = 0; r < 2; ++r)
        #pragma unroll
        for (int c = 0; c < 4; ++c)
            acc[r][c][0] = acc[r][c][1] = acc[r][c][2] = acc[r][c][3] = 0.f;
    int wch[4];
    #pragma unroll
    for (int c = 0; c < 4; ++c) wch[c] = (w * 64 + 16 * c + ln15) * wstr;
    bf16x8 wf0[4];
    #pragma unroll
    for (int c = 0; c < 4; ++c)
        wf0[c] = *(const bf16x8*)(WT + wch[c] + klane);
    for (int kc = 0; kc < kcn; ++kc) {
        bf16x8 wf1[4];
        if (kc + 1 < kcn) {
            #pragma unroll
            for (int c = 0; c < 4; ++c)
                wf1[c] = *(const bf16x8*)(WT + wch[c] + (kc + 1) * 32 + klane);
        }
        bf16x8 af[2];
        #pragma unroll
        for (int r = 0; r < 2; ++r)
            af[r] = *(const bf16x8*)&S[16 * r + ln15][kc * 32 + klane];
        #pragma unroll
        for (int r = 0; r < 2; ++r)
            #pragma unroll
            for (int c = 0; c < 4; ++c)
                acc[r][c] = __builtin_amdgcn_mfma_f32_16x16x32_bf16(wf0[c], af[r], acc[r][c], 0, 0, 0);
        #pragma unroll
        for (int c = 0; c < 4; ++c) wf0[c] = wf1[c];
    }
}

__device__ __forceinline__ void park32(ushort_t D[32][264], f32x4 acc[2][4],
                                       const float* __restrict__ bias,
                                       int act, int w, int ln15, int q)
{
    #pragma unroll
    for (int c = 0; c < 4; ++c) {
        float4 bv = bias ? *(const float4*)&bias[w * 64 + 16 * c + 4 * q]
                         : make_float4(0.f, 0.f, 0.f, 0.f);
        #pragma unroll
        for (int r = 0; r < 2; ++r) {
            float o0 = acc[r][c][0] + bv.x;
            float o1 = acc[r][c][1] + bv.y;
            float o2 = acc[r][c][2] + bv.z;
            float o3 = acc[r][c][3] + bv.w;
            if (act) { o0 = elu_f(o0); o1 = elu_f(o1); o2 = elu_f(o2); o3 = elu_f(o3); }
            ushort4 u;
            u.x = f2bf(o0); u.y = f2bf(o1); u.z = f2bf(o2); u.w = f2bf(o3);
            *(ushort4*)&D[16 * r + ln15][w * 64 + 16 * c + 4 * q] = u;
        }
    }
}

// ---- merged small chain: X[3200,K] (+opt X2) -> L1 -> L2 -> P,Q -----------
__global__ __launch_bounds__(256, 4)
void mlp_pq(const float* __restrict__ Xf, const float* __restrict__ Xf2,
            int Kreal, int kcN, float xscale,
            const ushort_t* __restrict__ W1T, const float* __restrict__ b1,
            const ushort_t* __restrict__ W2T, const float* __restrict__ b2,
            const ushort_t* __restrict__ WPT, int wsPQ,
            const float* __restrict__ bP, ushort_t* __restrict__ Pout,
            const ushort_t* __restrict__ WQT, ushort_t* __restrict__ Qout)
{
    __shared__ ushort_t Abuf[32][264];
    __shared__ ushort_t Bbuf[32][264];
    const int tid = threadIdx.x;
    const int w = tid >> 6;
    const int l = tid & 63;
    const int ln15 = l & 15;
    const int q = l >> 4;
    const int klane = 8 * q;
    const int Rbase = blockIdx.x * 32;

    {
        int row = tid >> 3, seg = tid & 7;
        if (seg < kcN) {
            ushort_t tmp[32];
            const float* src  = Xf + (size_t)(Rbase + row) * Kreal + seg * 32;
            const float* src2 = Xf2 ? Xf2 + (size_t)(Rbase + row) * Kreal + seg * 32
                                    : (const float*)nullptr;
            #pragma unroll
            for (int u = 0; u < 32; ++u) {
                float a = 0.f;
                if (seg * 32 + u < Kreal) {
                    a = src[u];
                    if (Xf2) a += src2[u];
                }
                tmp[u] = f2bf(a * xscale);
            }
            #pragma unroll
            for (int u = 0; u < 4; ++u)
                *(uint4*)&Abuf[row][seg * 32 + u * 8] = *(uint4*)&tmp[u * 8];
        }
    }
    __syncthreads();

    f32x4 acc[2][4];
    gemm32(Abuf, W1T, 256, kcN, w, ln15, klane, acc);
    park32(Bbuf, acc, b1, 1, w, ln15, q);
    __syncthreads();
    gemm32(Bbuf, W2T, 256, 8, w, ln15, klane, acc);
    park32(Abuf, acc, b2, 1, w, ln15, q);
    __syncthreads();
    gemm32(Abuf, WPT, wsPQ, 8, w, ln15, klane, acc);
    park32(Bbuf, acc, bP, 0, w, ln15, q);
    __syncthreads();
    f32x4 acq[2][4];
    gemm32(Abuf, WQT, wsPQ, 8, w, ln15, klane, acq);
    #pragma unroll
    for (int m = 0; m < 4; ++m) {
        int ch = tid + m * 256;
        int row = ch >> 5;
        int o = (ch & 31) * 8;
        *(uint4*)&Pout[(size_t)(Rbase + row) * 256 + o] = *(const uint4*)&Bbuf[row][o];
    }
    __syncthreads();
    park32(Bbuf, acq, nullptr, 0, w, ln15, q);
    __syncthreads();
    #pragma unroll
    for (int m = 0; m < 4; ++m) {
        int ch = tid + m * 256;
        int row = ch >> 5;
        int o = (ch & 31) * 8;
        *(uint4*)&Qout[(size_t)(Rbase + row) * 256 + o] = *(const uint4*)&Bbuf[row][o];
    }
}

// ---- wf prefetch helpers --------------------------------------------------
__device__ __forceinline__ void wf0_load(const ushort_t* __restrict__ WT,
                                         int wstr, int w, int ln15, int klane,
                                         bf16x8 wf0[2])
{
    #pragma unroll
    for (int c = 0; c < 2; ++c)
        wf0[c] = *(const bf16x8*)(WT + (w * 32 + 16 * c + ln15) * wstr + klane);
}

__device__ __forceinline__ void wf4_load(const ushort_t* __restrict__ WT,
                                         int wstr, int wc, int ln15, int klane,
                                         bf16x8 wf0[4])
{
    #pragma unroll
    for (int c = 0; c < 4; ++c)
        wf0[c] = *(const bf16x8*)(WT + (wc * 64 + 16 * c + ln15) * wstr + klane);
}

// ---- col-split 128-row GEMM core (wf0 preloaded): acc[8][2] (mlp2) --------
__device__ __forceinline__ void gemm128cs(const ushort_t As[128][264],
                                          const ushort_t* __restrict__ WT,
                                          int wstr, int w, int ln15, int klane,
                                          bf16x8 wf0[2], f32x4 acc[8][2])
{
    #pragma unroll
    for (int r = 0; r < 8; ++r)
        #pragma unroll
        for (int c = 0; c < 2; ++c)
            acc[r][c][0] = acc[r][c][1] = acc[r][c][2] = acc[r][c][3] = 0.f;
    int wch[2];
    #pragma unroll
    for (int c = 0; c < 2; ++c) wch[c] = (w * 32 + 16 * c + ln15) * wstr;
    #pragma unroll
    for (int kc = 0; kc < 8; ++kc) {
        bf16x8 wf1[2];
        if (kc < 7) {
            #pragma unroll
            for (int c = 0; c < 2; ++c)
                wf1[c] = *(const bf16x8*)(WT + wch[c] + (kc + 1) * 32 + klane);
        }
        #pragma unroll
        for (int g = 0; g < 2; ++g) {       // 4-row halves: bound live af regs
            bf16x8 af[4];
            #pragma unroll
            for (int r = 0; r < 4; ++r)
                af[r] = *(const bf16x8*)&As[16 * (4 * g + r) + ln15][kc * 32 + klane];
            #pragma unroll
            for (int r = 0; r < 4; ++r)
                #pragma unroll
                for (int c = 0; c < 2; ++c)
                    acc[4 * g + r][c] = __builtin_amdgcn_mfma_f32_16x16x32_bf16(wf0[c], af[r], acc[4 * g + r][c], 0, 0, 0);
        }
        #pragma unroll
        for (int c = 0; c < 2; ++c) wf0[c] = wf1[c];
    }
}

// ---- 2x4 128-row GEMM core: wave owns 64 rows x 64 cols, acc[4][4] --------
__device__ __forceinline__ void gemm128_24(const ushort_t As[128][264],
                                           const ushort_t* __restrict__ WT,
                                           int wstr, int wr, int wc,
                                           int ln15, int klane,
                                           bf16x8 wf0[4], f32x4 acc[4][4])
{
    #pragma unroll
    for (int r = 0; r < 4; ++r)
        #pragma unroll
        for (int c = 0; c < 4; ++c)
            acc[r][c][0] = acc[r][c][1] = acc[r][c][2] = acc[r][c][3] = 0.f;
    int wch[4];
    #pragma unroll
    for (int c = 0; c < 4; ++c) wch[c] = (wc * 64 + 16 * c + ln15) * wstr;
    #pragma unroll
    for (int kc = 0; kc < 8; ++kc) {
        bf16x8 wf1[4];
        if (kc < 7) {
            #pragma unroll
            for (int c = 0; c < 4; ++c)
                wf1[c] = *(const bf16x8*)(WT + wch[c] + (kc + 1) * 32 + klane);
        }
        #pragma unroll
        for (int rt = 0; rt < 4; ++rt) {
            bf16x8 af = *(const bf16x8*)&As[64 * wr + 16 * rt + ln15][kc * 32 + klane];
            #pragma unroll
            for (int ct = 0; ct < 4; ++ct)
                acc[rt][ct] = __builtin_amdgcn_mfma_f32_16x16x32_bf16(wf0[ct], af, acc[rt][ct], 0, 0, 0);
        }
        #pragma unroll
        for (int c = 0; c < 4; ++c) wf0[c] = wf1[c];
    }
}

// ---- edge kernel A (MLP2): reg e2n (A/B/C cumulative), wf0 prefetch -------
__global__ __launch_bounds__(512, 4)
void edge_mlp2(const ushort_t* __restrict__ Pb, const ushort_t* __restrict__ Qb,
               const ushort_t* __restrict__ W2T,
               const float* __restrict__ b2,
               ushort_t* __restrict__ Y,
               float* __restrict__ part0, float* __restrict__ part1)
{
    __shared__ ushort_t As[128][264];
    const int tid = threadIdx.x;
    const int w = tid >> 6;        // 0..7
    const int l = tid & 63;
    const int ln15 = l & 15;
    const int q = l >> 4;
    const int klane = 8 * q;
    const int Rbase = blockIdx.x * 128;

    // phase 1: hidden tile (512 threads cover 128 rows in one pass)
    {
        int row = tid >> 2;
        int R = Rbase + row;
        int b = R / E_EDGES;
        int e = R - b * E_EDGES;
        int i = e / 99;
        int k = e - 99 * i;
        int j = k + (k >= i ? 1 : 0);
        const ushort_t* prow = Pb + (size_t)(b * NNODE + j) * HID;
        const ushort_t* qrow = Qb + (size_t)(b * NNODE + i) * HID;
        int off = (tid & 3) * 8;
        uint4 pv[8], qv[8];
        #pragma unroll
        for (int u = 0; u < 8; ++u) {
            int o = off + u * 32;
            pv[u] = *(const uint4*)(prow + o);
            qv[u] = *(const uint4*)(qrow + o);
        }
        #pragma unroll
        for (int u = 0; u < 8; ++u) {
            int o = off + u * 32;
            union { uint4 v; ushort_t s[8]; } pu, qu, hu;
            pu.v = pv[u]; qu.v = qv[u];
            #pragma unroll
            for (int x = 0; x < 8; ++x)
                hu.s[x] = f2bf(elu_f(bf2f(pu.s[x]) + bf2f(qu.s[x])));
            *(uint4*)&As[row][o] = hu.v;
        }
    }
    bf16x8 wf0[2];
    wf0_load(W2T, 256, w, ln15, klane, wf0);
    __syncthreads();

    f32x4 acc[8][2];
    gemm128cs(As, W2T, 256, w, ln15, klane, wf0, acc);
    __syncthreads();

    // park x2 = ELU(acc + b2), accumulating segmented e2n sums in f32:
    //   sA = sum(all rows), sB = sum(row>=t1), sC = sum(row>=t2)
    const int g0   = Rbase / 99;
    const int off0 = Rbase - g0 * 99;
    const int t1   = 99 - off0;          // first row of group g0+1
    const int t2   = t1 + 99;            // first row of group g0+2
    float sA[8], sB[8], sC[8];
    #pragma unroll
    for (int j = 0; j < 8; ++j) { sA[j] = sB[j] = sC[j] = 0.f; }

    #pragma unroll
    for (int c = 0; c < 2; ++c) {
        float4 bv = *(const float4*)&b2[w * 32 + 16 * c + 4 * q];
        #pragma unroll
        for (int r = 0; r < 8; ++r) {
            int row = 16 * r + ln15;
            float o0 = elu_f(acc[r][c][0] + bv.x);
            float o1 = elu_f(acc[r][c][1] + bv.y);
            float o2 = elu_f(acc[r][c][2] + bv.z);
            float o3 = elu_f(acc[r][c][3] + bv.w);
            sA[c * 4 + 0] += o0; sA[c * 4 + 1] += o1;
            sA[c * 4 + 2] += o2; sA[c * 4 + 3] += o3;
            float m1 = (row >= t1) ? 1.f : 0.f;
            float m2 = (row >= t2) ? 1.f : 0.f;
            sB[c * 4 + 0] = fmaf(m1, o0, sB[c * 4 + 0]);
            sB[c * 4 + 1] = fmaf(m1, o1, sB[c * 4 + 1]);
            sB[c * 4 + 2] = fmaf(m1, o2, sB[c * 4 + 2]);
            sB[c * 4 + 3] = fmaf(m1, o3, sB[c * 4 + 3]);
            sC[c * 4 + 0] = fmaf(m2, o0, sC[c * 4 + 0]);
            sC[c * 4 + 1] = fmaf(m2, o1, sC[c * 4 + 1]);
            sC[c * 4 + 2] = fmaf(m2, o2, sC[c * 4 + 2]);
            sC[c * 4 + 3] = fmaf(m2, o3, sC[c * 4 + 3]);
            ushort4 u;
            u.x = f2bf(o0); u.y = f2bf(o1); u.z = f2bf(o2); u.w = f2bf(o3);
            *(ushort4*)&As[row][w * 32 + 16 * c + 4 * q] = u;
        }
    }
    // butterfly reduce over ln15 (16-lane groups)
    #pragma unroll
    for (int m = 1; m <= 8; m <<= 1) {
        #pragma unroll
        for (int j = 0; j < 8; ++j) {
            sA[j] += __shfl_xor(sA[j], m);
            sB[j] += __shfl_xor(sB[j], m);
            sC[j] += __shfl_xor(sC[j], m);
        }
    }
    __syncthreads();

    #pragma unroll
    for (int m = 0; m < 8; ++m) {
        int ch = tid + m * 512;
        int row = ch >> 5;
        int o = (ch & 31) * 8;
        *(uint4*)&Y[((size_t)(Rbase + row)) * 256 + o] = *(const uint4*)&As[row][o];
    }

    // e2n segment writes (ln15==0 lanes hold reduced sums)
    if (ln15 == 0) {
        float* d0 = (off0 != 0) ? part1 : part0;
        #pragma unroll
        for (int c = 0; c < 2; ++c) {
            int col = w * 32 + 16 * c + 4 * q;
            float4 v0, v1, v2;
            v0.x = sA[c * 4 + 0] - sB[c * 4 + 0];
            v0.y = sA[c * 4 + 1] - sB[c * 4 + 1];
            v0.z = sA[c * 4 + 2] - sB[c * 4 + 2];
            v0.w = sA[c * 4 + 3] - sB[c * 4 + 3];
            v1.x = sB[c * 4 + 0] - sC[c * 4 + 0];
            v1.y = sB[c * 4 + 1] - sC[c * 4 + 1];
            v1.z = sB[c * 4 + 2] - sC[c * 4 + 2];
            v1.w = sB[c * 4 + 3] - sC[c * 4 + 3];
            v2.x = sC[c * 4 + 0]; v2.y = sC[c * 4 + 1];
            v2.z = sC[c * 4 + 2]; v2.w = sC[c * 4 + 3];
            *(float4*)&d0[(size_t)g0 * 256 + col] = v0;
            *(float4*)&part0[(size_t)(g0 + 1) * 256 + col] = v1;
            if (t2 < 128)
                *(float4*)&part0[(size_t)(g0 + 2) * 256 + col] = v2;
        }
    }
}

// ---- edge kernel B (MLP4): 2x4 wave grid, Sc-LDS stats tail ---------------
__global__ __launch_bounds__(512, 4)
void edge_mlp4(const ushort_t* __restrict__ Pb, const ushort_t* __restrict__ Qb,
               const ushort_t* __restrict__ X2,
               const ushort_t* __restrict__ WaT, int wsA,
               const ushort_t* __restrict__ WbT, int wsB,
               const float* __restrict__ b2,
               ushort_t* __restrict__ Y, ushort_t* __restrict__ pstat)
{
    __shared__ ushort_t As[128][264];
    __shared__ float Sc[4][512];
    const int tid = threadIdx.x;
    const int w = tid >> 6;
    const int l = tid & 63;
    const int ln15 = l & 15;
    const int q = l >> 4;
    const int klane = 8 * q;
    const int wr = w >> 2;      // 0..1 row half
    const int wc = w & 3;       // 0..3 col quarter
    const int Rbase = blockIdx.x * 128;

    // stage x2 tile (batched, one pass with 512 threads)
    {
        int row = tid >> 2;
        const ushort_t* xrow = X2 + (size_t)(Rbase + row) * 256;
        int off = (tid & 3) * 8;
        uint4 xv[8];
        #pragma unroll
        for (int u = 0; u < 8; ++u) xv[u] = *(const uint4*)(xrow + off + u * 32);
        #pragma unroll
        for (int u = 0; u < 8; ++u) *(uint4*)&As[row][off + u * 32] = xv[u];
    }
    bf16x8 wfa[4];
    wf4_load(WaT, wsA, wc, ln15, klane, wfa);
    __syncthreads();

    f32x4 acc[4][4];
    // L1 GEMM: acc = x2tile @ W4a3
    gemm128_24(As, WaT, wsA, wr, wc, ln15, klane, wfa, acc);

    // gather offsets computed late (post-gemm1: not live through gemm1)
    int oP[4], oQ[4];
    #pragma unroll
    for (int rt = 0; rt < 4; ++rt) {
        int R = Rbase + 64 * wr + 16 * rt + ln15;
        int b = R / E_EDGES;
        int e = R - b * E_EDGES;
        int i = e / 99;
        int k = e - 99 * i;
        int j = k + (k >= i ? 1 : 0);
        oP[rt] = (b * NNODE + j) * HID;
        oQ[rt] = (b * NNODE + i) * HID;
    }
    __syncthreads();

    // hidden = ELU(acc + P[j] + Q[i]) -> As (batched per col-tile)
    #pragma unroll
    for (int ct = 0; ct < 4; ++ct) {
        int chn = wc * 64 + 16 * ct + 4 * q;
        ushort4 pv[4], qv[4];
        #pragma unroll
        for (int rt = 0; rt < 4; ++rt) {
            pv[rt] = *(const ushort4*)(Pb + oP[rt] + chn);
            qv[rt] = *(const ushort4*)(Qb + oQ[rt] + chn);
        }
        #pragma unroll
        for (int rt = 0; rt < 4; ++rt) {
            union { ushort4 v; ushort_t s[4]; } pu, qu;
            pu.v = pv[rt]; qu.v = qv[rt];
            ushort4 u;
            u.x = f2bf(elu_f(acc[rt][ct][0] + bf2f(pu.s[0]) + bf2f(qu.s[0])));
            u.y = f2bf(elu_f(acc[rt][ct][1] + bf2f(pu.s[1]) + bf2f(qu.s[1])));
            u.z = f2bf(elu_f(acc[rt][ct][2] + bf2f(pu.s[2]) + bf2f(qu.s[2])));
            u.w = f2bf(elu_f(acc[rt][ct][3] + bf2f(pu.s[3]) + bf2f(qu.s[3])));
            *(ushort4*)&As[64 * wr + 16 * rt + ln15][chn] = u;
        }
    }
    // wfb prefetch after hidden stores: held across one barrier only
    bf16x8 wfb[4];
    wf4_load(WbT, wsB, wc, ln15, klane, wfb);
    __syncthreads();

    // L2 GEMM: acc = hidden @ W4b
    gemm128_24(As, WbT, wsB, wr, wc, ln15, klane, wfb, acc);
    __syncthreads();

    // x4 = ELU(acc + b2) -> As park (no reg stats: tail uses Sc LDS)
    #pragma unroll
    for (int ct = 0; ct < 4; ++ct) {
        float4 bv = *(const float4*)&b2[wc * 64 + 16 * ct + 4 * q];
        #pragma unroll
        for (int rt = 0; rt < 4; ++rt) {
            ushort4 u;
            u.x = f2bf(elu_f(acc[rt][ct][0] + bv.x));
            u.y = f2bf(elu_f(acc[rt][ct][1] + bv.y));
            u.z = f2bf(elu_f(acc[rt][ct][2] + bv.z));
            u.w = f2bf(elu_f(acc[rt][ct][3] + bv.w));
            *(ushort4*)&As[64 * wr + 16 * rt + ln15][wc * 64 + 16 * ct + 4 * q] = u;
        }
    }
    __syncthreads();

    #pragma unroll
    for (int m = 0; m < 8; ++m) {
        int ch = tid + m * 512;
        int row = ch >> 5;
        int o = (ch & 31) * 8;
        *(uint4*)&Y[((size_t)(Rbase + row)) * 256 + o] = *(const uint4*)&As[row][o];
    }

    // distributed stats: 4 waves x 32 rows -> Sc, then 512-thread combine
    if (w < 4) {
        int c4 = l * 4;
        float s[4] = {0.f, 0.f, 0.f, 0.f};
        float qq[4] = {0.f, 0.f, 0.f, 0.f};
        for (int r = w * 32; r < w * 32 + 32; ++r) {
            union { ushort4 v; ushort_t e4[4]; } u;
            u.v = *(const ushort4*)&As[r][c4];
            #pragma unroll
            for (int g = 0; g < 4; ++g) {
                float v = bf2f(u.e4[g]);
                s[g] += v;
                qq[g] = fmaf(v, v, qq[g]);
            }
        }
        #pragma unroll
        for (int g = 0; g < 4; ++g) {
            Sc[w][c4 + g]       = s[g];
            Sc[w][256 + c4 + g] = qq[g];
        }
    }
    __syncthreads();
    {
        float v = Sc[0][tid] + Sc[1][tid] + Sc[2][tid] + Sc[3][tid];
        pstat[(size_t)blockIdx.x * 512 + tid] = f2bf(v);
    }
}

// ---- reduce per-block partials -> stats -----------------------------------
__global__ __launch_bounds__(256)
void reduce_stats(const ushort_t* __restrict__ pstat, float* __restrict__ stats)
{
    int c = threadIdx.x;
    float s = 0.f, q = 0.f;
    for (int b = blockIdx.x; b < NBLK2; b += 64) {
        size_t base = (size_t)b * 512;
        s += bf2f(pstat[base + c]);
        q += bf2f(pstat[base + 256 + c]);
    }
    atomicAdd(&stats[c], s);
    atomicAdd(&stats[256 + c], q);
}

// ---- fold BN + fc into Wfold[256][2], bfold[2] ----------------------------
__global__ __launch_bounds__(256)
void fold_kernel(const float* __restrict__ stats,
                 const float* __restrict__ gamma, const float* __restrict__ beta,
                 const float* __restrict__ fcW, const float* __restrict__ fcb,
                 float* __restrict__ fold)
{
    __shared__ float red0[256], red1[256];
    int c = threadIdx.x;
    float mean  = stats[c] * (1.f / M_BIG);
    float var   = stats[256 + c] * (1.f / M_BIG) - mean * mean;
    float inv   = rsqrtf(var + 1e-5f);
    float scale = inv * gamma[c];
    float sh    = beta[c] - mean * scale;
    float w0 = fcW[c * 2 + 0], w1 = fcW[c * 2 + 1];
    fold[c * 2 + 0] = scale * w0;
    fold[c * 2 + 1] = scale * w1;
    red0[c] = sh * w0;
    red1[c] = sh * w1;
    __syncthreads();
    for (int off = 128; off > 0; off >>= 1) {
        if (c < off) { red0[c] += red0[c + off]; red1[c] += red1[c + off]; }
        __syncthreads();
    }
    if (c == 0) {
        fold[512] = red0[0] + fcb[0];
        fold[513] = red1[0] + fcb[1];
    }
}

// ---- final: out[R][2] = x4_row . Wfold + bfold ----------------------------
__global__ __launch_bounds__(256)
void final_kernel(const ushort_t* __restrict__ x4, const float* __restrict__ fold,
                  float* __restrict__ out)
{
    int tid  = threadIdx.x;
    int l32  = tid & 31;
    int g    = tid >> 5;
    int R = blockIdx.x * 8 + g;
    int c0 = l32 * 8;
    union { uint4 qv; ushort_t s[8]; } u;
    u.qv = *(const uint4*)(x4 + (size_t)R * 256 + c0);
    float a0 = 0.f, a1 = 0.f;
    #pragma unroll
    for (int j = 0; j < 8; ++j) {
        float v = bf2f(u.s[j]);
        a0 = fmaf(v, fold[(c0 + j) * 2 + 0], a0);
        a1 = fmaf(v, fold[(c0 + j) * 2 + 1], a1);
    }
    #pragma unroll
    for (int off = 16; off > 0; off >>= 1) {
        a0 += __shfl_down(a0, off);
        a1 += __shfl_down(a1, off);
    }
    if (l32 == 0) {
        out[(size_t)R * 2 + 0] = a0 + fold[512];
        out[(size_t)R * 2 + 1] = a1 + fold[513];
    }
}

extern "C" void kernel_launch(void* const* d_in, const int* in_sizes, int n_in,
                              void* d_out, int out_size, void* d_ws, size_t ws_size,
                              hipStream_t stream)
{
    (void)in_sizes; (void)n_in; (void)out_size; (void)ws_size;

    const float* inputs = (const float*)d_in[0];
    const float* m1W1 = (const float*)d_in[3];
    const float* m1b1 = (const float*)d_in[4];
    const float* m1W2 = (const float*)d_in[5];
    const float* m1b2 = (const float*)d_in[6];
    const float* m2W1 = (const float*)d_in[7];
    const float* m2b1 = (const float*)d_in[8];
    const float* m2W2 = (const float*)d_in[9];
    const float* m2b2 = (const float*)d_in[10];
    const float* m3W1 = (const float*)d_in[11];
    const float* m3b1 = (const float*)d_in[12];
    const float* m3W2 = (const float*)d_in[13];
    const float* m3b2 = (const float*)d_in[14];
    const float* m4W1 = (const float*)d_in[15];
    const float* m4b1 = (const float*)d_in[16];
    const float* m4W2 = (const float*)d_in[17];
    const float* m4b2 = (const float*)d_in[18];
    const float* gamma = (const float*)d_in[19];
    const float* beta  = (const float*)d_in[20];
    const float* fcW   = (const float*)d_in[21];
    const float* fcb   = (const float*)d_in[22];
    float* out = (float*)d_out;

    // ---- workspace layout (byte-identical total to known-good R13/R16) ----
    char* ws = (char*)d_ws;
    const size_t BIGB = (size_t)M_BIG * 256 * 2;      // 162,201,600
    const size_t HB   = (size_t)M_SMALL * 256 * 2;    // 1,638,400
    const size_t SM4  = (size_t)M_SMALL * 256 * 4;    // 3,276,800
    ushort_t* bigX     = (ushort_t*)ws;                         // x2 then x4
    ushort_t* pstat    = (ushort_t*)(ws + BIGB);                // 2.53 MB region (2*HB)
    float*    part1    = (float*)(ws + BIGB);                   // aliases pstat (disjoint in time)
    float*    part0    = (float*)(ws + BIGB + 2 * HB);          // SM4 bytes
    ushort_t* Pbuf     = (ushort_t*)(ws + BIGB + 2 * HB + SM4);
    ushort_t* Qbuf     = (ushort_t*)(ws + BIGB + 3 * HB + SM4);
    float*    stats    = (float*)(ws + BIGB + 4 * HB + SM4);
    float*    fold     = stats + 512;
    ushort_t* w1t      = (ushort_t*)(ws + BIGB + 4 * HB + SM4 + 8192);
    ushort_t* w1bt     = w1t  + 256 * 256;
    ushort_t* w2pt     = w1bt + 256 * 256;     // [256][512]
    ushort_t* w2t      = w2pt + 256 * 512;
    ushort_t* w3at     = w2t  + 256 * 256;
    ushort_t* w3bt     = w3at + 256 * 256;
    ushort_t* w4pt     = w3bt + 256 * 256;     // [256][768]
    ushort_t* w4bt     = w4pt + 256 * 768;

    hipMemsetAsync(stats, 0, 2048, stream);
    hipMemsetAsync(part1, 0, SM4, stream);     // continuation slots default 0

    dim3 blk(256);
    dim3 blk512(512);
    wcvt_all<<<176, blk, 0, stream>>>(m1W1, m1W2, m2W1, m2W2, m3W1, m3W2, m4W1, m4W2,
                                      w1t, w1bt, w2pt, w2t, w3at, w3bt, w4pt, w4bt);
    // MLP1 + PQ2 (h1 never leaves LDS)
    mlp_pq<<<100, blk, 0, stream>>>(inputs, nullptr, 200, 7, 1.f,
                                    w1t, m1b1, w1bt, m1b2,
                                    w2pt, 512, m2b1, Pbuf,
                                    w2pt + 256, Qbuf);
    // edge MLP2 -> x2 + e2n 2-slot partials
    edge_mlp2<<<NBLK2, blk512, 0, stream>>>(Pbuf, Qbuf, w2t, m2b2, bigX, part0, part1);
    // MLP3 + PQ4 (incoming = (part0+part1)/9900)
    mlp_pq<<<100, blk, 0, stream>>>(part0, part1, 256, 8, 1.f / 9900.f,
                                    w3at, m3b1, w3bt, m3b2,
                                    w4pt, 768, m4b1, Pbuf,
                                    w4pt + 256, Qbuf);
    // edge MLP4 (skip weight = w4pt cols 512.., stride 768)
    edge_mlp4<<<NBLK2, blk512, 0, stream>>>(Pbuf, Qbuf, bigX,
                                            w4pt + 512, 768, w4bt, 256,
                                            m4b2, bigX, pstat);
    reduce_stats<<<64, blk, 0, stream>>>(pstat, stats);
    fold_kernel<<<1, blk, 0, stream>>>(stats, gamma, beta, fcW, fcb, fold);
    final_kernel<<<M_BIG / 8, blk, 0, stream>>>(bigX, fold, out);
}

// Round 10
// 452.912 us; speedup vs baseline: 1.1485x; 1.1485x over previous
//
#include <hip/hip_runtime.h>
#include <math.h>

// ---------------------------------------------------------------------------
// MLPEncoder (NRI encoder) on MI355X — round 23: revert mlp4 to R21 (2x4
// remap refuted: conflicts -36% but spill +20MB and MfmaUtil 19->14, dur
// 182->241). Col-split gemm is the best mapping under the 64V+64A split.
// New: mlp_pq split into P-half / Q-half blocks (grid 100 -> 200): each
// block runs a 3-GEMM chain (L1,L2,P) or (L1,L2,Q) instead of 4 — the
// small chain is latency-bound and was using only 100/256 CUs.
// ---------------------------------------------------------------------------

typedef unsigned short ushort_t;
typedef __bf16 bf16x8 __attribute__((ext_vector_type(8)));
typedef float  f32x4  __attribute__((ext_vector_type(4)));

#define E_EDGES 9900
#define NNODE   100
#define HID     256
#define M_BIG   316800
#define M_SMALL 3200
#define NBLK2   (M_BIG / 128)   /* 2475 */

__device__ __forceinline__ float bf2f(ushort_t u) {
    union { unsigned int i; float f; } v; v.i = ((unsigned int)u) << 16; return v.f;
}
__device__ __forceinline__ ushort_t f2bf(float f) {
    union { __bf16 h; ushort_t u; } v; v.h = (__bf16)f; return v.u;   // RNE
}
__device__ __forceinline__ float elu_f(float x) {
    return x > 0.f ? x : (__expf(x) - 1.f);
}

// ---- convert all weights to chan-major bf16 WT[col][K] --------------------
__global__ __launch_bounds__(256)
void wcvt_all(const float* __restrict__ s0, const float* __restrict__ s1,
              const float* __restrict__ s2, const float* __restrict__ s3,
              const float* __restrict__ s4, const float* __restrict__ s5,
              const float* __restrict__ s6, const float* __restrict__ s7,
              ushort_t* d0, ushort_t* d1, ushort_t* d2, ushort_t* d3,
              ushort_t* d4, ushort_t* d5, ushort_t* d6, ushort_t* d7)
{
    int bid = blockIdx.x;
    const float* S; ushort_t* D; int Kd, Kr, t;
    if      (bid < 16)  { S = s0; D = d0; Kd = 256; Kr = 200; t = bid; }
    else if (bid < 32)  { S = s1; D = d1; Kd = 256; Kr = 256; t = bid - 16; }
    else if (bid < 64)  { S = s2; D = d2; Kd = 512; Kr = 512; t = bid - 32; }
    else if (bid < 80)  { S = s3; D = d3; Kd = 256; Kr = 256; t = bid - 64; }
    else if (bid < 96)  { S = s4; D = d4; Kd = 256; Kr = 256; t = bid - 80; }
    else if (bid < 112) { S = s5; D = d5; Kd = 256; Kr = 256; t = bid - 96; }
    else if (bid < 160) { S = s6; D = d6; Kd = 768; Kr = 768; t = bid - 112; }
    else                { S = s7; D = d7; Kd = 256; Kr = 256; t = bid - 160; }
    int k0 = (t >> 2) * 64, c0 = (t & 3) * 64;
    __shared__ float Sh[64][65];
    int tid = threadIdx.x;
    #pragma unroll
    for (int i = 0; i < 16; ++i) {
        int idx = tid + i * 256;
        int kk = idx >> 6, cc = idx & 63;
        Sh[kk][cc] = (k0 + kk < Kr) ? S[(size_t)(k0 + kk) * 256 + c0 + cc] : 0.f;
    }
    __syncthreads();
    int col = tid & 63;
    int kb  = (tid >> 6) * 16;
    ushort_t* dst = D + (size_t)(c0 + col) * Kd + k0 + kb;
    #pragma unroll
    for (int jj = 0; jj < 4; ++jj) {
        ushort4 u;
        u.x = f2bf(Sh[kb + 4 * jj + 0][col]);
        u.y = f2bf(Sh[kb + 4 * jj + 1][col]);
        u.z = f2bf(Sh[kb + 4 * jj + 2][col]);
        u.w = f2bf(Sh[kb + 4 * jj + 3][col]);
        *(ushort4*)(dst + 4 * jj) = u;
    }
}

// ---- 2-row-tile GEMM helper over a 32x264 LDS tile (small chain) ----------
__device__ __forceinline__ void gemm32(const ushort_t S[32][264],
                                       const ushort_t* __restrict__ WT,
                                       int wstr, int kcn,
                                       int w, int ln15, int klane,
                                       f32x4 acc[2][4])
{
    #pragma unroll
    for (int r = 0; r < 2; ++r)
        #pragma unroll
        for (int c = 0; c < 4; ++c)
            acc[r][c][0] = acc[r][c][1] = acc[r][c][2] = acc[r][c][3] = 0.f;
    int wch[4];
    #pragma unroll
    for (int c = 0; c < 4; ++c) wch[c] = (w * 64 + 16 * c + ln15) * wstr;
    bf16x8 wf0[4];
    #pragma unroll
    for (int c = 0; c < 4; ++c)
        wf0[c] = *(const bf16x8*)(WT + wch[c] + klane);
    for (int kc = 0; kc < kcn; ++kc) {
        bf16x8 wf1[4];
        if (kc + 1 < kcn) {
            #pragma unroll
            for (int c = 0; c < 4; ++c)
                wf1[c] = *(const bf16x8*)(WT + wch[c] + (kc + 1) * 32 + klane);
        }
        bf16x8 af[2];
        #pragma unroll
        for (int r = 0; r < 2; ++r)
            af[r] = *(const bf16x8*)&S[16 * r + ln15][kc * 32 + klane];
        #pragma unroll
        for (int r = 0; r < 2; ++r)
            #pragma unroll
            for (int c = 0; c < 4; ++c)
                acc[r][c] = __builtin_amdgcn_mfma_f32_16x16x32_bf16(wf0[c], af[r], acc[r][c], 0, 0, 0);
        #pragma unroll
        for (int c = 0; c < 4; ++c) wf0[c] = wf1[c];
    }
}

__device__ __forceinline__ void park32(ushort_t D[32][264], f32x4 acc[2][4],
                                       const float* __restrict__ bias,
                                       int act, int w, int ln15, int q)
{
    #pragma unroll
    for (int c = 0; c < 4; ++c) {
        float4 bv = bias ? *(const float4*)&bias[w * 64 + 16 * c + 4 * q]
                         : make_float4(0.f, 0.f, 0.f, 0.f);
        #pragma unroll
        for (int r = 0; r < 2; ++r) {
            float o0 = acc[r][c][0] + bv.x;
            float o1 = acc[r][c][1] + bv.y;
            float o2 = acc[r][c][2] + bv.z;
            float o3 = acc[r][c][3] + bv.w;
            if (act) { o0 = elu_f(o0); o1 = elu_f(o1); o2 = elu_f(o2); o3 = elu_f(o3); }
            ushort4 u;
            u.x = f2bf(o0); u.y = f2bf(o1); u.z = f2bf(o2); u.w = f2bf(o3);
            *(ushort4*)&D[16 * r + ln15][w * 64 + 16 * c + 4 * q] = u;
        }
    }
}

// ---- merged small chain, P/Q split: grid 2*NB blocks.
//   blocks [0,NB)   : X -> L1 -> L2 -> P
//   blocks [NB,2NB) : X -> L1 -> L2 -> Q   (L1/L2 recomputed; latency-bound)
__global__ __launch_bounds__(256, 4)
void mlp_pq(const float* __restrict__ Xf, const float* __restrict__ Xf2,
            int Kreal, int kcN, float xscale,
            const ushort_t* __restrict__ W1T, const float* __restrict__ b1,
            const ushort_t* __restrict__ W2T, const float* __restrict__ b2,
            const ushort_t* __restrict__ WPT, int wsPQ,
            const float* __restrict__ bP, ushort_t* __restrict__ Pout,
            const ushort_t* __restrict__ WQT, ushort_t* __restrict__ Qout)
{
    __shared__ ushort_t Abuf[32][264];
    __shared__ ushort_t Bbuf[32][264];
    const int tid = threadIdx.x;
    const int w = tid >> 6;
    const int l = tid & 63;
    const int ln15 = l & 15;
    const int q = l >> 4;
    const int klane = 8 * q;
    const int half = blockIdx.x >= (int)(gridDim.x >> 1);
    const int blk  = half ? blockIdx.x - (int)(gridDim.x >> 1) : blockIdx.x;
    const int Rbase = blk * 32;

    {
        int row = tid >> 3, seg = tid & 7;
        if (seg < kcN) {
            ushort_t tmp[32];
            const float* src  = Xf + (size_t)(Rbase + row) * Kreal + seg * 32;
            const float* src2 = Xf2 ? Xf2 + (size_t)(Rbase + row) * Kreal + seg * 32
                                    : (const float*)nullptr;
            #pragma unroll
            for (int u = 0; u < 32; ++u) {
                float a = 0.f;
                if (seg * 32 + u < Kreal) {
                    a = src[u];
                    if (Xf2) a += src2[u];
                }
                tmp[u] = f2bf(a * xscale);
            }
            #pragma unroll
            for (int u = 0; u < 4; ++u)
                *(uint4*)&Abuf[row][seg * 32 + u * 8] = *(uint4*)&tmp[u * 8];
        }
    }
    __syncthreads();

    f32x4 acc[2][4];
    gemm32(Abuf, W1T, 256, kcN, w, ln15, klane, acc);
    park32(Bbuf, acc, b1, 1, w, ln15, q);
    __syncthreads();
    gemm32(Bbuf, W2T, 256, 8, w, ln15, klane, acc);
    park32(Abuf, acc, b2, 1, w, ln15, q);
    __syncthreads();

    const ushort_t* WT = half ? WQT : WPT;
    ushort_t* Out = half ? Qout : Pout;
    gemm32(Abuf, WT, wsPQ, 8, w, ln15, klane, acc);
    park32(Bbuf, acc, half ? nullptr : bP, 0, w, ln15, q);
    __syncthreads();
    #pragma unroll
    for (int m = 0; m < 4; ++m) {
        int ch = tid + m * 256;
        int row = ch >> 5;
        int o = (ch & 31) * 8;
        *(uint4*)&Out[(size_t)(Rbase + row) * 256 + o] = *(const uint4*)&Bbuf[row][o];
    }
}

// ---- wf0 prefetch for col-split GEMM --------------------------------------
__device__ __forceinline__ void wf0_load(const ushort_t* __restrict__ WT,
                                         int wstr, int w, int ln15, int klane,
                                         bf16x8 wf0[2])
{
    #pragma unroll
    for (int c = 0; c < 2; ++c)
        wf0[c] = *(const bf16x8*)(WT + (w * 32 + 16 * c + ln15) * wstr + klane);
}

// ---- col-split 128-row GEMM core (wf0 preloaded): acc[8][2] ---------------
__device__ __forceinline__ void gemm128cs(const ushort_t As[128][264],
                                          const ushort_t* __restrict__ WT,
                                          int wstr, int w, int ln15, int klane,
                                          bf16x8 wf0[2], f32x4 acc[8][2])
{
    #pragma unroll
    for (int r = 0; r < 8; ++r)
        #pragma unroll
        for (int c = 0; c < 2; ++c)
            acc[r][c][0] = acc[r][c][1] = acc[r][c][2] = acc[r][c][3] = 0.f;
    int wch[2];
    #pragma unroll
    for (int c = 0; c < 2; ++c) wch[c] = (w * 32 + 16 * c + ln15) * wstr;
    #pragma unroll
    for (int kc = 0; kc < 8; ++kc) {
        bf16x8 wf1[2];
        if (kc < 7) {
            #pragma unroll
            for (int c = 0; c < 2; ++c)
                wf1[c] = *(const bf16x8*)(WT + wch[c] + (kc + 1) * 32 + klane);
        }
        #pragma unroll
        for (int g = 0; g < 2; ++g) {       // 4-row halves: bound live af regs
            bf16x8 af[4];
            #pragma unroll
            for (int r = 0; r < 4; ++r)
                af[r] = *(const bf16x8*)&As[16 * (4 * g + r) + ln15][kc * 32 + klane];
            #pragma unroll
            for (int r = 0; r < 4; ++r)
                #pragma unroll
                for (int c = 0; c < 2; ++c)
                    acc[4 * g + r][c] = __builtin_amdgcn_mfma_f32_16x16x32_bf16(wf0[c], af[r], acc[4 * g + r][c], 0, 0, 0);
        }
        #pragma unroll
        for (int c = 0; c < 2; ++c) wf0[c] = wf1[c];
    }
}

// ---- edge kernel A (MLP2): reg e2n (A/B/C cumulative), wf0 prefetch -------
__global__ __launch_bounds__(512, 4)
void edge_mlp2(const ushort_t* __restrict__ Pb, const ushort_t* __restrict__ Qb,
               const ushort_t* __restrict__ W2T,
               const float* __restrict__ b2,
               ushort_t* __restrict__ Y,
               float* __restrict__ part0, float* __restrict__ part1)
{
    __shared__ ushort_t As[128][264];
    const int tid = threadIdx.x;
    const int w = tid >> 6;        // 0..7
    const int l = tid & 63;
    const int ln15 = l & 15;
    const int q = l >> 4;
    const int klane = 8 * q;
    const int Rbase = blockIdx.x * 128;

    // phase 1: hidden tile (512 threads cover 128 rows in one pass)
    {
        int row = tid >> 2;
        int R = Rbase + row;
        int b = R / E_EDGES;
        int e = R - b * E_EDGES;
        int i = e / 99;
        int k = e - 99 * i;
        int j = k + (k >= i ? 1 : 0);
        const ushort_t* prow = Pb + (size_t)(b * NNODE + j) * HID;
        const ushort_t* qrow = Qb + (size_t)(b * NNODE + i) * HID;
        int off = (tid & 3) * 8;
        uint4 pv[8], qv[8];
        #pragma unroll
        for (int u = 0; u < 8; ++u) {
            int o = off + u * 32;
            pv[u] = *(const uint4*)(prow + o);
            qv[u] = *(const uint4*)(qrow + o);
        }
        #pragma unroll
        for (int u = 0; u < 8; ++u) {
            int o = off + u * 32;
            union { uint4 v; ushort_t s[8]; } pu, qu, hu;
            pu.v = pv[u]; qu.v = qv[u];
            #pragma unroll
            for (int x = 0; x < 8; ++x)
                hu.s[x] = f2bf(elu_f(bf2f(pu.s[x]) + bf2f(qu.s[x])));
            *(uint4*)&As[row][o] = hu.v;
        }
    }
    bf16x8 wf0[2];
    wf0_load(W2T, 256, w, ln15, klane, wf0);
    __syncthreads();

    f32x4 acc[8][2];
    gemm128cs(As, W2T, 256, w, ln15, klane, wf0, acc);
    __syncthreads();

    // park x2 = ELU(acc + b2), accumulating segmented e2n sums in f32:
    //   sA = sum(all rows), sB = sum(row>=t1), sC = sum(row>=t2)
    const int g0   = Rbase / 99;
    const int off0 = Rbase - g0 * 99;
    const int t1   = 99 - off0;          // first row of group g0+1
    const int t2   = t1 + 99;            // first row of group g0+2
    float sA[8], sB[8], sC[8];
    #pragma unroll
    for (int j = 0; j < 8; ++j) { sA[j] = sB[j] = sC[j] = 0.f; }

    #pragma unroll
    for (int c = 0; c < 2; ++c) {
        float4 bv = *(const float4*)&b2[w * 32 + 16 * c + 4 * q];
        #pragma unroll
        for (int r = 0; r < 8; ++r) {
            int row = 16 * r + ln15;
            float o0 = elu_f(acc[r][c][0] + bv.x);
            float o1 = elu_f(acc[r][c][1] + bv.y);
            float o2 = elu_f(acc[r][c][2] + bv.z);
            float o3 = elu_f(acc[r][c][3] + bv.w);
            sA[c * 4 + 0] += o0; sA[c * 4 + 1] += o1;
            sA[c * 4 + 2] += o2; sA[c * 4 + 3] += o3;
            float m1 = (row >= t1) ? 1.f : 0.f;
            float m2 = (row >= t2) ? 1.f : 0.f;
            sB[c * 4 + 0] = fmaf(m1, o0, sB[c * 4 + 0]);
            sB[c * 4 + 1] = fmaf(m1, o1, sB[c * 4 + 1]);
            sB[c * 4 + 2] = fmaf(m1, o2, sB[c * 4 + 2]);
            sB[c * 4 + 3] = fmaf(m1, o3, sB[c * 4 + 3]);
            sC[c * 4 + 0] = fmaf(m2, o0, sC[c * 4 + 0]);
            sC[c * 4 + 1] = fmaf(m2, o1, sC[c * 4 + 1]);
            sC[c * 4 + 2] = fmaf(m2, o2, sC[c * 4 + 2]);
            sC[c * 4 + 3] = fmaf(m2, o3, sC[c * 4 + 3]);
            ushort4 u;
            u.x = f2bf(o0); u.y = f2bf(o1); u.z = f2bf(o2); u.w = f2bf(o3);
            *(ushort4*)&As[row][w * 32 + 16 * c + 4 * q] = u;
        }
    }
    // butterfly reduce over ln15 (16-lane groups)
    #pragma unroll
    for (int m = 1; m <= 8; m <<= 1) {
        #pragma unroll
        for (int j = 0; j < 8; ++j) {
            sA[j] += __shfl_xor(sA[j], m);
            sB[j] += __shfl_xor(sB[j], m);
            sC[j] += __shfl_xor(sC[j], m);
        }
    }
    __syncthreads();

    #pragma unroll
    for (int m = 0; m < 8; ++m) {
        int ch = tid + m * 512;
        int row = ch >> 5;
        int o = (ch & 31) * 8;
        *(uint4*)&Y[((size_t)(Rbase + row)) * 256 + o] = *(const uint4*)&As[row][o];
    }

    // e2n segment writes (ln15==0 lanes hold reduced sums)
    if (ln15 == 0) {
        float* d0 = (off0 != 0) ? part1 : part0;
        #pragma unroll
        for (int c = 0; c < 2; ++c) {
            int col = w * 32 + 16 * c + 4 * q;
            float4 v0, v1, v2;
            v0.x = sA[c * 4 + 0] - sB[c * 4 + 0];
            v0.y = sA[c * 4 + 1] - sB[c * 4 + 1];
            v0.z = sA[c * 4 + 2] - sB[c * 4 + 2];
            v0.w = sA[c * 4 + 3] - sB[c * 4 + 3];
            v1.x = sB[c * 4 + 0] - sC[c * 4 + 0];
            v1.y = sB[c * 4 + 1] - sC[c * 4 + 1];
            v1.z = sB[c * 4 + 2] - sC[c * 4 + 2];
            v1.w = sB[c * 4 + 3] - sC[c * 4 + 3];
            v2.x = sC[c * 4 + 0]; v2.y = sC[c * 4 + 1];
            v2.z = sC[c * 4 + 2]; v2.w = sC[c * 4 + 3];
            *(float4*)&d0[(size_t)g0 * 256 + col] = v0;
            *(float4*)&part0[(size_t)(g0 + 1) * 256 + col] = v1;
            if (t2 < 128)
                *(float4*)&part0[(size_t)(g0 + 2) * 256 + col] = v2;
        }
    }
}

// ---- edge kernel B (MLP4): Sc-LDS stats tail, late oP/oQ, wfa prefetch ----
__global__ __launch_bounds__(512, 4)
void edge_mlp4(const ushort_t* __restrict__ Pb, const ushort_t* __restrict__ Qb,
               const ushort_t* __restrict__ X2,
               const ushort_t* __restrict__ WaT, int wsA,
               const ushort_t* __restrict__ WbT, int wsB,
               const float* __restrict__ b2,
               ushort_t* __restrict__ Y, ushort_t* __restrict__ pstat)
{
    __shared__ ushort_t As[128][264];
    __shared__ float Sc[4][512];
    const int tid = threadIdx.x;
    const int w = tid >> 6;
    const int l = tid & 63;
    const int ln15 = l & 15;
    const int q = l >> 4;
    const int klane = 8 * q;
    const int Rbase = blockIdx.x * 128;

    // stage x2 tile (batched, one pass with 512 threads)
    {
        int row = tid >> 2;
        const ushort_t* xrow = X2 + (size_t)(Rbase + row) * 256;
        int off = (tid & 3) * 8;
        uint4 xv[8];
        #pragma unroll
        for (int u = 0; u < 8; ++u) xv[u] = *(const uint4*)(xrow + off + u * 32);
        #pragma unroll
        for (int u = 0; u < 8; ++u) *(uint4*)&As[row][off + u * 32] = xv[u];
    }
    bf16x8 wfa[2];
    wf0_load(WaT, wsA, w, ln15, klane, wfa);
    __syncthreads();

    f32x4 acc[8][2];
    // L1 GEMM: acc = x2tile @ W4a3
    gemm128cs(As, WaT, wsA, w, ln15, klane, wfa, acc);

    // gather offsets computed late (post-gemm1: not live through gemm1)
    int oP[8], oQ[8];
    #pragma unroll
    for (int r = 0; r < 8; ++r) {
        int R = Rbase + 16 * r + ln15;
        int b = R / E_EDGES;
        int e = R - b * E_EDGES;
        int i = e / 99;
        int k = e - 99 * i;
        int j = k + (k >= i ? 1 : 0);
        oP[r] = (b * NNODE + j) * HID;
        oQ[r] = (b * NNODE + i) * HID;
    }
    __syncthreads();

    // hidden = ELU(acc + P[j] + Q[i]) -> As (batched per col-tile)
    #pragma unroll
    for (int c = 0; c < 2; ++c) {
        int ch = w * 32 + 16 * c + 4 * q;
        ushort4 pv[8], qv[8];
        #pragma unroll
        for (int r = 0; r < 8; ++r) {
            pv[r] = *(const ushort4*)(Pb + oP[r] + ch);
            qv[r] = *(const ushort4*)(Qb + oQ[r] + ch);
        }
        #pragma unroll
        for (int r = 0; r < 8; ++r) {
            union { ushort4 v; ushort_t s[4]; } pu, qu;
            pu.v = pv[r]; qu.v = qv[r];
            ushort4 u;
            u.x = f2bf(elu_f(acc[r][c][0] + bf2f(pu.s[0]) + bf2f(qu.s[0])));
            u.y = f2bf(elu_f(acc[r][c][1] + bf2f(pu.s[1]) + bf2f(qu.s[1])));
            u.z = f2bf(elu_f(acc[r][c][2] + bf2f(pu.s[2]) + bf2f(qu.s[2])));
            u.w = f2bf(elu_f(acc[r][c][3] + bf2f(pu.s[3]) + bf2f(qu.s[3])));
            *(ushort4*)&As[16 * r + ln15][ch] = u;
        }
    }
    // wfb prefetch after hidden stores: held across one barrier only
    bf16x8 wfb[2];
    wf0_load(WbT, wsB, w, ln15, klane, wfb);
    __syncthreads();

    // L2 GEMM: acc = hidden @ W4b
    gemm128cs(As, WbT, wsB, w, ln15, klane, wfb, acc);
    __syncthreads();

    // x4 = ELU(acc + b2) -> As park (no reg stats: tail uses Sc LDS)
    #pragma unroll
    for (int c = 0; c < 2; ++c) {
        float4 bv = *(const float4*)&b2[w * 32 + 16 * c + 4 * q];
        #pragma unroll
        for (int r = 0; r < 8; ++r) {
            ushort4 u;
            u.x = f2bf(elu_f(acc[r][c][0] + bv.x));
            u.y = f2bf(elu_f(acc[r][c][1] + bv.y));
            u.z = f2bf(elu_f(acc[r][c][2] + bv.z));
            u.w = f2bf(elu_f(acc[r][c][3] + bv.w));
            *(ushort4*)&As[16 * r + ln15][w * 32 + 16 * c + 4 * q] = u;
        }
    }
    __syncthreads();

    #pragma unroll
    for (int m = 0; m < 8; ++m) {
        int ch = tid + m * 512;
        int row = ch >> 5;
        int o = (ch & 31) * 8;
        *(uint4*)&Y[((size_t)(Rbase + row)) * 256 + o] = *(const uint4*)&As[row][o];
    }

    // distributed stats: 4 waves x 32 rows -> Sc, then 512-thread combine
    if (w < 4) {
        int c4 = l * 4;
        float s[4] = {0.f, 0.f, 0.f, 0.f};
        float qq[4] = {0.f, 0.f, 0.f, 0.f};
        for (int r = w * 32; r < w * 32 + 32; ++r) {
            union { ushort4 v; ushort_t e4[4]; } u;
            u.v = *(const ushort4*)&As[r][c4];
            #pragma unroll
            for (int g = 0; g < 4; ++g) {
                float v = bf2f(u.e4[g]);
                s[g] += v;
                qq[g] = fmaf(v, v, qq[g]);
            }
        }
        #pragma unroll
        for (int g = 0; g < 4; ++g) {
            Sc[w][c4 + g]       = s[g];
            Sc[w][256 + c4 + g] = qq[g];
        }
    }
    __syncthreads();
    {
        float v = Sc[0][tid] + Sc[1][tid] + Sc[2][tid] + Sc[3][tid];
        pstat[(size_t)blockIdx.x * 512 + tid] = f2bf(v);
    }
}

// ---- reduce per-block partials -> stats -----------------------------------
__global__ __launch_bounds__(256)
void reduce_stats(const ushort_t* __restrict__ pstat, float* __restrict__ stats)
{
    int c = threadIdx.x;
    float s = 0.f, q = 0.f;
    for (int b = blockIdx.x; b < NBLK2; b += 64) {
        size_t base = (size_t)b * 512;
        s += bf2f(pstat[base + c]);
        q += bf2f(pstat[base + 256 + c]);
    }
    atomicAdd(&stats[c], s);
    atomicAdd(&stats[256 + c], q);
}

// ---- fold BN + fc into Wfold[256][2], bfold[2] ----------------------------
__global__ __launch_bounds__(256)
void fold_kernel(const float* __restrict__ stats,
                 const float* __restrict__ gamma, const float* __restrict__ beta,
                 const float* __restrict__ fcW, const float* __restrict__ fcb,
                 float* __restrict__ fold)
{
    __shared__ float red0[256], red1[256];
    int c = threadIdx.x;
    float mean  = stats[c] * (1.f / M_BIG);
    float var   = stats[256 + c] * (1.f / M_BIG) - mean * mean;
    float inv   = rsqrtf(var + 1e-5f);
    float scale = inv * gamma[c];
    float sh    = beta[c] - mean * scale;
    float w0 = fcW[c * 2 + 0], w1 = fcW[c * 2 + 1];
    fold[c * 2 + 0] = scale * w0;
    fold[c * 2 + 1] = scale * w1;
    red0[c] = sh * w0;
    red1[c] = sh * w1;
    __syncthreads();
    for (int off = 128; off > 0; off >>= 1) {
        if (c < off) { red0[c] += red0[c + off]; red1[c] += red1[c + off]; }
        __syncthreads();
    }
    if (c == 0) {
        fold[512] = red0[0] + fcb[0];
        fold[513] = red1[0] + fcb[1];
    }
}

// ---- final: out[R][2] = x4_row . Wfold + bfold ----------------------------
__global__ __launch_bounds__(256)
void final_kernel(const ushort_t* __restrict__ x4, const float* __restrict__ fold,
                  float* __restrict__ out)
{
    int tid  = threadIdx.x;
    int l32  = tid & 31;
    int g    = tid >> 5;
    int R = blockIdx.x * 8 + g;
    int c0 = l32 * 8;
    union { uint4 qv; ushort_t s[8]; } u;
    u.qv = *(const uint4*)(x4 + (size_t)R * 256 + c0);
    float a0 = 0.f, a1 = 0.f;
    #pragma unroll
    for (int j = 0; j < 8; ++j) {
        float v = bf2f(u.s[j]);
        a0 = fmaf(v, fold[(c0 + j) * 2 + 0], a0);
        a1 = fmaf(v, fold[(c0 + j) * 2 + 1], a1);
    }
    #pragma unroll
    for (int off = 16; off > 0; off >>= 1) {
        a0 += __shfl_down(a0, off);
        a1 += __shfl_down(a1, off);
    }
    if (l32 == 0) {
        out[(size_t)R * 2 + 0] = a0 + fold[512];
        out[(size_t)R * 2 + 1] = a1 + fold[513];
    }
}

extern "C" void kernel_launch(void* const* d_in, const int* in_sizes, int n_in,
                              void* d_out, int out_size, void* d_ws, size_t ws_size,
                              hipStream_t stream)
{
    (void)in_sizes; (void)n_in; (void)out_size; (void)ws_size;

    const float* inputs = (const float*)d_in[0];
    const float* m1W1 = (const float*)d_in[3];
    const float* m1b1 = (const float*)d_in[4];
    const float* m1W2 = (const float*)d_in[5];
    const float* m1b2 = (const float*)d_in[6];
    const float* m2W1 = (const float*)d_in[7];
    const float* m2b1 = (const float*)d_in[8];
    const float* m2W2 = (const float*)d_in[9];
    const float* m2b2 = (const float*)d_in[10];
    const float* m3W1 = (const float*)d_in[11];
    const float* m3b1 = (const float*)d_in[12];
    const float* m3W2 = (const float*)d_in[13];
    const float* m3b2 = (const float*)d_in[14];
    const float* m4W1 = (const float*)d_in[15];
    const float* m4b1 = (const float*)d_in[16];
    const float* m4W2 = (const float*)d_in[17];
    const float* m4b2 = (const float*)d_in[18];
    const float* gamma = (const float*)d_in[19];
    const float* beta  = (const float*)d_in[20];
    const float* fcW   = (const float*)d_in[21];
    const float* fcb   = (const float*)d_in[22];
    float* out = (float*)d_out;

    // ---- workspace layout (byte-identical total to known-good R13/R16) ----
    char* ws = (char*)d_ws;
    const size_t BIGB = (size_t)M_BIG * 256 * 2;      // 162,201,600
    const size_t HB   = (size_t)M_SMALL * 256 * 2;    // 1,638,400
    const size_t SM4  = (size_t)M_SMALL * 256 * 4;    // 3,276,800
    ushort_t* bigX     = (ushort_t*)ws;                         // x2 then x4
    ushort_t* pstat    = (ushort_t*)(ws + BIGB);                // 2.53 MB region (2*HB)
    float*    part1    = (float*)(ws + BIGB);                   // aliases pstat (disjoint in time)
    float*    part0    = (float*)(ws + BIGB + 2 * HB);          // SM4 bytes
    ushort_t* Pbuf     = (ushort_t*)(ws + BIGB + 2 * HB + SM4);
    ushort_t* Qbuf     = (ushort_t*)(ws + BIGB + 3 * HB + SM4);
    float*    stats    = (float*)(ws + BIGB + 4 * HB + SM4);
    float*    fold     = stats + 512;
    ushort_t* w1t      = (ushort_t*)(ws + BIGB + 4 * HB + SM4 + 8192);
    ushort_t* w1bt     = w1t  + 256 * 256;
    ushort_t* w2pt     = w1bt + 256 * 256;     // [256][512]
    ushort_t* w2t      = w2pt + 256 * 512;
    ushort_t* w3at     = w2t  + 256 * 256;
    ushort_t* w3bt     = w3at + 256 * 256;
    ushort_t* w4pt     = w3bt + 256 * 256;     // [256][768]
    ushort_t* w4bt     = w4pt + 256 * 768;

    hipMemsetAsync(stats, 0, 2048, stream);
    hipMemsetAsync(part1, 0, SM4, stream);     // continuation slots default 0

    dim3 blk(256);
    dim3 blk512(512);
    wcvt_all<<<176, blk, 0, stream>>>(m1W1, m1W2, m2W1, m2W2, m3W1, m3W2, m4W1, m4W2,
                                      w1t, w1bt, w2pt, w2t, w3at, w3bt, w4pt, w4bt);
    // MLP1 + PQ2 (P/Q halves in parallel, 200 blocks)
    mlp_pq<<<200, blk, 0, stream>>>(inputs, nullptr, 200, 7, 1.f,
                                    w1t, m1b1, w1bt, m1b2,
                                    w2pt, 512, m2b1, Pbuf,
                                    w2pt + 256, Qbuf);
    // edge MLP2 -> x2 + e2n 2-slot partials
    edge_mlp2<<<NBLK2, blk512, 0, stream>>>(Pbuf, Qbuf, w2t, m2b2, bigX, part0, part1);
    // MLP3 + PQ4 (incoming = (part0+part1)/9900; P/Q halves, 200 blocks)
    mlp_pq<<<200, blk, 0, stream>>>(part0, part1, 256, 8, 1.f / 9900.f,
                                    w3at, m3b1, w3bt, m3b2,
                                    w4pt, 768, m4b1, Pbuf,
                                    w4pt + 256, Qbuf);
    // edge MLP4 (skip weight = w4pt cols 512.., stride 768)
    edge_mlp4<<<NBLK2, blk512, 0, stream>>>(Pbuf, Qbuf, bigX,
                                            w4pt + 512, 768, w4bt, 256,
                                            m4b2, bigX, pstat);
    reduce_stats<<<64, blk, 0, stream>>>(pstat, stats);
    fold_kernel<<<1, blk, 0, stream>>>(stats, gamma, beta, fcW, fcb, fold);
    final_kernel<<<M_BIG / 8, blk, 0, stream>>>(bigX, fold, out);
}

// Round 11
// 445.673 us; speedup vs baseline: 1.1672x; 1.0162x over previous
//
#include <hip/hip_runtime.h>
#include <math.h>

// ---------------------------------------------------------------------------
// MLPEncoder (NRI encoder) on MI355X — round 24: R23 + mlp2 e2n tail moved
// from registers (24 live floats during park + 48 shfl_xor => spill risk,
// same pattern as mlp4's R19 regression) to the Sc-LDS distributed form that
// won in mlp4 (R21): plain park, then 4 waves x 32 rows accumulate segmented
// cumulative sums into Sc2[4][768] (12 KB), 256-thread combine writes
// part0/part1. LDS 67584 -> 79872 (still 2 blocks/CU). Everything else R23.
// ---------------------------------------------------------------------------

typedef unsigned short ushort_t;
typedef __bf16 bf16x8 __attribute__((ext_vector_type(8)));
typedef float  f32x4  __attribute__((ext_vector_type(4)));

#define E_EDGES 9900
#define NNODE   100
#define HID     256
#define M_BIG   316800
#define M_SMALL 3200
#define NBLK2   (M_BIG / 128)   /* 2475 */

__device__ __forceinline__ float bf2f(ushort_t u) {
    union { unsigned int i; float f; } v; v.i = ((unsigned int)u) << 16; return v.f;
}
__device__ __forceinline__ ushort_t f2bf(float f) {
    union { __bf16 h; ushort_t u; } v; v.h = (__bf16)f; return v.u;   // RNE
}
__device__ __forceinline__ float elu_f(float x) {
    return x > 0.f ? x : (__expf(x) - 1.f);
}

// ---- convert all weights to chan-major bf16 WT[col][K] --------------------
__global__ __launch_bounds__(256)
void wcvt_all(const float* __restrict__ s0, const float* __restrict__ s1,
              const float* __restrict__ s2, const float* __restrict__ s3,
              const float* __restrict__ s4, const float* __restrict__ s5,
              const float* __restrict__ s6, const float* __restrict__ s7,
              ushort_t* d0, ushort_t* d1, ushort_t* d2, ushort_t* d3,
              ushort_t* d4, ushort_t* d5, ushort_t* d6, ushort_t* d7)
{
    int bid = blockIdx.x;
    const float* S; ushort_t* D; int Kd, Kr, t;
    if      (bid < 16)  { S = s0; D = d0; Kd = 256; Kr = 200; t = bid; }
    else if (bid < 32)  { S = s1; D = d1; Kd = 256; Kr = 256; t = bid - 16; }
    else if (bid < 64)  { S = s2; D = d2; Kd = 512; Kr = 512; t = bid - 32; }
    else if (bid < 80)  { S = s3; D = d3; Kd = 256; Kr = 256; t = bid - 64; }
    else if (bid < 96)  { S = s4; D = d4; Kd = 256; Kr = 256; t = bid - 80; }
    else if (bid < 112) { S = s5; D = d5; Kd = 256; Kr = 256; t = bid - 96; }
    else if (bid < 160) { S = s6; D = d6; Kd = 768; Kr = 768; t = bid - 112; }
    else                { S = s7; D = d7; Kd = 256; Kr = 256; t = bid - 160; }
    int k0 = (t >> 2) * 64, c0 = (t & 3) * 64;
    __shared__ float Sh[64][65];
    int tid = threadIdx.x;
    #pragma unroll
    for (int i = 0; i < 16; ++i) {
        int idx = tid + i * 256;
        int kk = idx >> 6, cc = idx & 63;
        Sh[kk][cc] = (k0 + kk < Kr) ? S[(size_t)(k0 + kk) * 256 + c0 + cc] : 0.f;
    }
    __syncthreads();
    int col = tid & 63;
    int kb  = (tid >> 6) * 16;
    ushort_t* dst = D + (size_t)(c0 + col) * Kd + k0 + kb;
    #pragma unroll
    for (int jj = 0; jj < 4; ++jj) {
        ushort4 u;
        u.x = f2bf(Sh[kb + 4 * jj + 0][col]);
        u.y = f2bf(Sh[kb + 4 * jj + 1][col]);
        u.z = f2bf(Sh[kb + 4 * jj + 2][col]);
        u.w = f2bf(Sh[kb + 4 * jj + 3][col]);
        *(ushort4*)(dst + 4 * jj) = u;
    }
}

// ---- 2-row-tile GEMM helper over a 32x264 LDS tile (small chain) ----------
__device__ __forceinline__ void gemm32(const ushort_t S[32][264],
                                       const ushort_t* __restrict__ WT,
                                       int wstr, int kcn,
                                       int w, int ln15, int klane,
                                       f32x4 acc[2][4])
{
    #pragma unroll
    for (int r = 0; r < 2; ++r)
        #pragma unroll
        for (int c = 0; c < 4; ++c)
            acc[r][c][0] = acc[r][c][1] = acc[r][c][2] = acc[r][c][3] = 0.f;
    int wch[4];
    #pragma unroll
    for (int c = 0; c < 4; ++c) wch[c] = (w * 64 + 16 * c + ln15) * wstr;
    bf16x8 wf0[4];
    #pragma unroll
    for (int c = 0; c < 4; ++c)
        wf0[c] = *(const bf16x8*)(WT + wch[c] + klane);
    for (int kc = 0; kc < kcn; ++kc) {
        bf16x8 wf1[4];
        if (kc + 1 < kcn) {
            #pragma unroll
            for (int c = 0; c < 4; ++c)
                wf1[c] = *(const bf16x8*)(WT + wch[c] + (kc + 1) * 32 + klane);
        }
        bf16x8 af[2];
        #pragma unroll
        for (int r = 0; r < 2; ++r)
            af[r] = *(const bf16x8*)&S[16 * r + ln15][kc * 32 + klane];
        #pragma unroll
        for (int r = 0; r < 2; ++r)
            #pragma unroll
            for (int c = 0; c < 4; ++c)
                acc[r][c] = __builtin_amdgcn_mfma_f32_16x16x32_bf16(wf0[c], af[r], acc[r][c], 0, 0, 0);
        #pragma unroll
        for (int c = 0; c < 4; ++c) wf0[c] = wf1[c];
    }
}

__device__ __forceinline__ void park32(ushort_t D[32][264], f32x4 acc[2][4],
                                       const float* __restrict__ bias,
                                       int act, int w, int ln15, int q)
{
    #pragma unroll
    for (int c = 0; c < 4; ++c) {
        float4 bv = bias ? *(const float4*)&bias[w * 64 + 16 * c + 4 * q]
                         : make_float4(0.f, 0.f, 0.f, 0.f);
        #pragma unroll
        for (int r = 0; r < 2; ++r) {
            float o0 = acc[r][c][0] + bv.x;
            float o1 = acc[r][c][1] + bv.y;
            float o2 = acc[r][c][2] + bv.z;
            float o3 = acc[r][c][3] + bv.w;
            if (act) { o0 = elu_f(o0); o1 = elu_f(o1); o2 = elu_f(o2); o3 = elu_f(o3); }
            ushort4 u;
            u.x = f2bf(o0); u.y = f2bf(o1); u.z = f2bf(o2); u.w = f2bf(o3);
            *(ushort4*)&D[16 * r + ln15][w * 64 + 16 * c + 4 * q] = u;
        }
    }
}

// ---- merged small chain, P/Q split: grid 2*NB blocks.
//   blocks [0,NB)   : X -> L1 -> L2 -> P
//   blocks [NB,2NB) : X -> L1 -> L2 -> Q   (L1/L2 recomputed; latency-bound)
__global__ __launch_bounds__(256, 4)
void mlp_pq(const float* __restrict__ Xf, const float* __restrict__ Xf2,
            int Kreal, int kcN, float xscale,
            const ushort_t* __restrict__ W1T, const float* __restrict__ b1,
            const ushort_t* __restrict__ W2T, const float* __restrict__ b2,
            const ushort_t* __restrict__ WPT, int wsPQ,
            const float* __restrict__ bP, ushort_t* __restrict__ Pout,
            const ushort_t* __restrict__ WQT, ushort_t* __restrict__ Qout)
{
    __shared__ ushort_t Abuf[32][264];
    __shared__ ushort_t Bbuf[32][264];
    const int tid = threadIdx.x;
    const int w = tid >> 6;
    const int l = tid & 63;
    const int ln15 = l & 15;
    const int q = l >> 4;
    const int klane = 8 * q;
    const int half = blockIdx.x >= (int)(gridDim.x >> 1);
    const int blk  = half ? blockIdx.x - (int)(gridDim.x >> 1) : blockIdx.x;
    const int Rbase = blk * 32;

    {
        int row = tid >> 3, seg = tid & 7;
        if (seg < kcN) {
            ushort_t tmp[32];
            const float* src  = Xf + (size_t)(Rbase + row) * Kreal + seg * 32;
            const float* src2 = Xf2 ? Xf2 + (size_t)(Rbase + row) * Kreal + seg * 32
                                    : (const float*)nullptr;
            #pragma unroll
            for (int u = 0; u < 32; ++u) {
                float a = 0.f;
                if (seg * 32 + u < Kreal) {
                    a = src[u];
                    if (Xf2) a += src2[u];
                }
                tmp[u] = f2bf(a * xscale);
            }
            #pragma unroll
            for (int u = 0; u < 4; ++u)
                *(uint4*)&Abuf[row][seg * 32 + u * 8] = *(uint4*)&tmp[u * 8];
        }
    }
    __syncthreads();

    f32x4 acc[2][4];
    gemm32(Abuf, W1T, 256, kcN, w, ln15, klane, acc);
    park32(Bbuf, acc, b1, 1, w, ln15, q);
    __syncthreads();
    gemm32(Bbuf, W2T, 256, 8, w, ln15, klane, acc);
    park32(Abuf, acc, b2, 1, w, ln15, q);
    __syncthreads();

    const ushort_t* WT = half ? WQT : WPT;
    ushort_t* Out = half ? Qout : Pout;
    gemm32(Abuf, WT, wsPQ, 8, w, ln15, klane, acc);
    park32(Bbuf, acc, half ? nullptr : bP, 0, w, ln15, q);
    __syncthreads();
    #pragma unroll
    for (int m = 0; m < 4; ++m) {
        int ch = tid + m * 256;
        int row = ch >> 5;
        int o = (ch & 31) * 8;
        *(uint4*)&Out[(size_t)(Rbase + row) * 256 + o] = *(const uint4*)&Bbuf[row][o];
    }
}

// ---- wf0 prefetch for col-split GEMM --------------------------------------
__device__ __forceinline__ void wf0_load(const ushort_t* __restrict__ WT,
                                         int wstr, int w, int ln15, int klane,
                                         bf16x8 wf0[2])
{
    #pragma unroll
    for (int c = 0; c < 2; ++c)
        wf0[c] = *(const bf16x8*)(WT + (w * 32 + 16 * c + ln15) * wstr + klane);
}

// ---- col-split 128-row GEMM core (wf0 preloaded): acc[8][2] ---------------
__device__ __forceinline__ void gemm128cs(const ushort_t As[128][264],
                                          const ushort_t* __restrict__ WT,
                                          int wstr, int w, int ln15, int klane,
                                          bf16x8 wf0[2], f32x4 acc[8][2])
{
    #pragma unroll
    for (int r = 0; r < 8; ++r)
        #pragma unroll
        for (int c = 0; c < 2; ++c)
            acc[r][c][0] = acc[r][c][1] = acc[r][c][2] = acc[r][c][3] = 0.f;
    int wch[2];
    #pragma unroll
    for (int c = 0; c < 2; ++c) wch[c] = (w * 32 + 16 * c + ln15) * wstr;
    #pragma unroll
    for (int kc = 0; kc < 8; ++kc) {
        bf16x8 wf1[2];
        if (kc < 7) {
            #pragma unroll
            for (int c = 0; c < 2; ++c)
                wf1[c] = *(const bf16x8*)(WT + wch[c] + (kc + 1) * 32 + klane);
        }
        #pragma unroll
        for (int g = 0; g < 2; ++g) {       // 4-row halves: bound live af regs
            bf16x8 af[4];
            #pragma unroll
            for (int r = 0; r < 4; ++r)
                af[r] = *(const bf16x8*)&As[16 * (4 * g + r) + ln15][kc * 32 + klane];
            #pragma unroll
            for (int r = 0; r < 4; ++r)
                #pragma unroll
                for (int c = 0; c < 2; ++c)
                    acc[4 * g + r][c] = __builtin_amdgcn_mfma_f32_16x16x32_bf16(wf0[c], af[r], acc[4 * g + r][c], 0, 0, 0);
        }
        #pragma unroll
        for (int c = 0; c < 2; ++c) wf0[c] = wf1[c];
    }
}

// ---- edge kernel A (MLP2): Sc-LDS segmented e2n tail, wf0 prefetch --------
__global__ __launch_bounds__(512, 4)
void edge_mlp2(const ushort_t* __restrict__ Pb, const ushort_t* __restrict__ Qb,
               const ushort_t* __restrict__ W2T,
               const float* __restrict__ b2,
               ushort_t* __restrict__ Y,
               float* __restrict__ part0, float* __restrict__ part1)
{
    __shared__ ushort_t As[128][264];
    __shared__ float Sc2[4][768];
    const int tid = threadIdx.x;
    const int w = tid >> 6;        // 0..7
    const int l = tid & 63;
    const int ln15 = l & 15;
    const int q = l >> 4;
    const int klane = 8 * q;
    const int Rbase = blockIdx.x * 128;

    // phase 1: hidden tile (512 threads cover 128 rows in one pass)
    {
        int row = tid >> 2;
        int R = Rbase + row;
        int b = R / E_EDGES;
        int e = R - b * E_EDGES;
        int i = e / 99;
        int k = e - 99 * i;
        int j = k + (k >= i ? 1 : 0);
        const ushort_t* prow = Pb + (size_t)(b * NNODE + j) * HID;
        const ushort_t* qrow = Qb + (size_t)(b * NNODE + i) * HID;
        int off = (tid & 3) * 8;
        uint4 pv[8], qv[8];
        #pragma unroll
        for (int u = 0; u < 8; ++u) {
            int o = off + u * 32;
            pv[u] = *(const uint4*)(prow + o);
            qv[u] = *(const uint4*)(qrow + o);
        }
        #pragma unroll
        for (int u = 0; u < 8; ++u) {
            int o = off + u * 32;
            union { uint4 v; ushort_t s[8]; } pu, qu, hu;
            pu.v = pv[u]; qu.v = qv[u];
            #pragma unroll
            for (int x = 0; x < 8; ++x)
                hu.s[x] = f2bf(elu_f(bf2f(pu.s[x]) + bf2f(qu.s[x])));
            *(uint4*)&As[row][o] = hu.v;
        }
    }
    bf16x8 wf0[2];
    wf0_load(W2T, 256, w, ln15, klane, wf0);
    __syncthreads();

    f32x4 acc[8][2];
    gemm128cs(As, W2T, 256, w, ln15, klane, wf0, acc);
    __syncthreads();

    // park x2 = ELU(acc + b2) -> As (simple; no live accumulators)
    #pragma unroll
    for (int c = 0; c < 2; ++c) {
        float4 bv = *(const float4*)&b2[w * 32 + 16 * c + 4 * q];
        #pragma unroll
        for (int r = 0; r < 8; ++r) {
            ushort4 u;
            u.x = f2bf(elu_f(acc[r][c][0] + bv.x));
            u.y = f2bf(elu_f(acc[r][c][1] + bv.y));
            u.z = f2bf(elu_f(acc[r][c][2] + bv.z));
            u.w = f2bf(elu_f(acc[r][c][3] + bv.w));
            *(ushort4*)&As[16 * r + ln15][w * 32 + 16 * c + 4 * q] = u;
        }
    }
    __syncthreads();

    #pragma unroll
    for (int m = 0; m < 8; ++m) {
        int ch = tid + m * 512;
        int row = ch >> 5;
        int o = (ch & 31) * 8;
        *(uint4*)&Y[((size_t)(Rbase + row)) * 256 + o] = *(const uint4*)&As[row][o];
    }

    // distributed segmented e2n: 4 waves x 32 rows -> cumulative sums in Sc2
    const int g0   = Rbase / 99;
    const int off0 = Rbase - g0 * 99;
    const int t1   = 99 - off0;          // first row of group g0+1
    const int t2   = t1 + 99;            // first row of group g0+2
    if (w < 4) {
        int c4 = l * 4;
        float cA[4] = {0.f, 0.f, 0.f, 0.f};
        float cB[4] = {0.f, 0.f, 0.f, 0.f};
        float cC[4] = {0.f, 0.f, 0.f, 0.f};
        for (int r = w * 32; r < w * 32 + 32; ++r) {
            union { ushort4 v; ushort_t e4[4]; } u;
            u.v = *(const ushort4*)&As[r][c4];
            float m1 = (r >= t1) ? 1.f : 0.f;
            float m2 = (r >= t2) ? 1.f : 0.f;
            #pragma unroll
            for (int g = 0; g < 4; ++g) {
                float v = bf2f(u.e4[g]);
                cA[g] += v;
                cB[g] = fmaf(m1, v, cB[g]);
                cC[g] = fmaf(m2, v, cC[g]);
            }
        }
        #pragma unroll
        for (int g = 0; g < 4; ++g) {
            Sc2[w][c4 + g]       = cA[g];
            Sc2[w][256 + c4 + g] = cB[g];
            Sc2[w][512 + c4 + g] = cC[g];
        }
    }
    __syncthreads();
    if (tid < 256) {
        float A = Sc2[0][tid] + Sc2[1][tid] + Sc2[2][tid] + Sc2[3][tid];
        float B = Sc2[0][256 + tid] + Sc2[1][256 + tid] + Sc2[2][256 + tid] + Sc2[3][256 + tid];
        float C = Sc2[0][512 + tid] + Sc2[1][512 + tid] + Sc2[2][512 + tid] + Sc2[3][512 + tid];
        float* d0 = (off0 != 0) ? part1 : part0;
        d0[(size_t)g0 * 256 + tid] = A - B;
        part0[(size_t)(g0 + 1) * 256 + tid] = B - C;
        if (t2 < 128)
            part0[(size_t)(g0 + 2) * 256 + tid] = C;
    }
}

// ---- edge kernel B (MLP4): Sc-LDS stats tail, late oP/oQ, wfa prefetch ----
__global__ __launch_bounds__(512, 4)
void edge_mlp4(const ushort_t* __restrict__ Pb, const ushort_t* __restrict__ Qb,
               const ushort_t* __restrict__ X2,
               const ushort_t* __restrict__ WaT, int wsA,
               const ushort_t* __restrict__ WbT, int wsB,
               const float* __restrict__ b2,
               ushort_t* __restrict__ Y, ushort_t* __restrict__ pstat)
{
    __shared__ ushort_t As[128][264];
    __shared__ float Sc[4][512];
    const int tid = threadIdx.x;
    const int w = tid >> 6;
    const int l = tid & 63;
    const int ln15 = l & 15;
    const int q = l >> 4;
    const int klane = 8 * q;
    const int Rbase = blockIdx.x * 128;

    // stage x2 tile (batched, one pass with 512 threads)
    {
        int row = tid >> 2;
        const ushort_t* xrow = X2 + (size_t)(Rbase + row) * 256;
        int off = (tid & 3) * 8;
        uint4 xv[8];
        #pragma unroll
        for (int u = 0; u < 8; ++u) xv[u] = *(const uint4*)(xrow + off + u * 32);
        #pragma unroll
        for (int u = 0; u < 8; ++u) *(uint4*)&As[row][off + u * 32] = xv[u];
    }
    bf16x8 wfa[2];
    wf0_load(WaT, wsA, w, ln15, klane, wfa);
    __syncthreads();

    f32x4 acc[8][2];
    // L1 GEMM: acc = x2tile @ W4a3
    gemm128cs(As, WaT, wsA, w, ln15, klane, wfa, acc);

    // gather offsets computed late (post-gemm1: not live through gemm1)
    int oP[8], oQ[8];
    #pragma unroll
    for (int r = 0; r < 8; ++r) {
        int R = Rbase + 16 * r + ln15;
        int b = R / E_EDGES;
        int e = R - b * E_EDGES;
        int i = e / 99;
        int k = e - 99 * i;
        int j = k + (k >= i ? 1 : 0);
        oP[r] = (b * NNODE + j) * HID;
        oQ[r] = (b * NNODE + i) * HID;
    }
    __syncthreads();

    // hidden = ELU(acc + P[j] + Q[i]) -> As (batched per col-tile)
    #pragma unroll
    for (int c = 0; c < 2; ++c) {
        int ch = w * 32 + 16 * c + 4 * q;
        ushort4 pv[8], qv[8];
        #pragma unroll
        for (int r = 0; r < 8; ++r) {
            pv[r] = *(const ushort4*)(Pb + oP[r] + ch);
            qv[r] = *(const ushort4*)(Qb + oQ[r] + ch);
        }
        #pragma unroll
        for (int r = 0; r < 8; ++r) {
            union { ushort4 v; ushort_t s[4]; } pu, qu;
            pu.v = pv[r]; qu.v = qv[r];
            ushort4 u;
            u.x = f2bf(elu_f(acc[r][c][0] + bf2f(pu.s[0]) + bf2f(qu.s[0])));
            u.y = f2bf(elu_f(acc[r][c][1] + bf2f(pu.s[1]) + bf2f(qu.s[1])));
            u.z = f2bf(elu_f(acc[r][c][2] + bf2f(pu.s[2]) + bf2f(qu.s[2])));
            u.w = f2bf(elu_f(acc[r][c][3] + bf2f(pu.s[3]) + bf2f(qu.s[3])));
            *(ushort4*)&As[16 * r + ln15][ch] = u;
        }
    }
    // wfb prefetch after hidden stores: held across one barrier only
    bf16x8 wfb[2];
    wf0_load(WbT, wsB, w, ln15, klane, wfb);
    __syncthreads();

    // L2 GEMM: acc = hidden @ W4b
    gemm128cs(As, WbT, wsB, w, ln15, klane, wfb, acc);
    __syncthreads();

    // x4 = ELU(acc + b2) -> As park (no reg stats: tail uses Sc LDS)
    #pragma unroll
    for (int c = 0; c < 2; ++c) {
        float4 bv = *(const float4*)&b2[w * 32 + 16 * c + 4 * q];
        #pragma unroll
        for (int r = 0; r < 8; ++r) {
            ushort4 u;
            u.x = f2bf(elu_f(acc[r][c][0] + bv.x));
            u.y = f2bf(elu_f(acc[r][c][1] + bv.y));
            u.z = f2bf(elu_f(acc[r][c][2] + bv.z));
            u.w = f2bf(elu_f(acc[r][c][3] + bv.w));
            *(ushort4*)&As[16 * r + ln15][w * 32 + 16 * c + 4 * q] = u;
        }
    }
    __syncthreads();

    #pragma unroll
    for (int m = 0; m < 8; ++m) {
        int ch = tid + m * 512;
        int row = ch >> 5;
        int o = (ch & 31) * 8;
        *(uint4*)&Y[((size_t)(Rbase + row)) * 256 + o] = *(const uint4*)&As[row][o];
    }

    // distributed stats: 4 waves x 32 rows -> Sc, then 512-thread combine
    if (w < 4) {
        int c4 = l * 4;
        float s[4] = {0.f, 0.f, 0.f, 0.f};
        float qq[4] = {0.f, 0.f, 0.f, 0.f};
        for (int r = w * 32; r < w * 32 + 32; ++r) {
            union { ushort4 v; ushort_t e4[4]; } u;
            u.v = *(const ushort4*)&As[r][c4];
            #pragma unroll
            for (int g = 0; g < 4; ++g) {
                float v = bf2f(u.e4[g]);
                s[g] += v;
                qq[g] = fmaf(v, v, qq[g]);
            }
        }
        #pragma unroll
        for (int g = 0; g < 4; ++g) {
            Sc[w][c4 + g]       = s[g];
            Sc[w][256 + c4 + g] = qq[g];
        }
    }
    __syncthreads();
    {
        float v = Sc[0][tid] + Sc[1][tid] + Sc[2][tid] + Sc[3][tid];
        pstat[(size_t)blockIdx.x * 512 + tid] = f2bf(v);
    }
}

// ---- reduce per-block partials -> stats -----------------------------------
__global__ __launch_bounds__(256)
void reduce_stats(const ushort_t* __restrict__ pstat, float* __restrict__ stats)
{
    int c = threadIdx.x;
    float s = 0.f, q = 0.f;
    for (int b = blockIdx.x; b < NBLK2; b += 64) {
        size_t base = (size_t)b * 512;
        s += bf2f(pstat[base + c]);
        q += bf2f(pstat[base + 256 + c]);
    }
    atomicAdd(&stats[c], s);
    atomicAdd(&stats[256 + c], q);
}

// ---- fold BN + fc into Wfold[256][2], bfold[2] ----------------------------
__global__ __launch_bounds__(256)
void fold_kernel(const float* __restrict__ stats,
                 const float* __restrict__ gamma, const float* __restrict__ beta,
                 const float* __restrict__ fcW, const float* __restrict__ fcb,
                 float* __restrict__ fold)
{
    __shared__ float red0[256], red1[256];
    int c = threadIdx.x;
    float mean  = stats[c] * (1.f / M_BIG);
    float var   = stats[256 + c] * (1.f / M_BIG) - mean * mean;
    float inv   = rsqrtf(var + 1e-5f);
    float scale = inv * gamma[c];
    float sh    = beta[c] - mean * scale;
    float w0 = fcW[c * 2 + 0], w1 = fcW[c * 2 + 1];
    fold[c * 2 + 0] = scale * w0;
    fold[c * 2 + 1] = scale * w1;
    red0[c] = sh * w0;
    red1[c] = sh * w1;
    __syncthreads();
    for (int off = 128; off > 0; off >>= 1) {
        if (c < off) { red0[c] += red0[c + off]; red1[c] += red1[c + off]; }
        __syncthreads();
    }
    if (c == 0) {
        fold[512] = red0[0] + fcb[0];
        fold[513] = red1[0] + fcb[1];
    }
}

// ---- final: out[R][2] = x4_row . Wfold + bfold ----------------------------
__global__ __launch_bounds__(256)
void final_kernel(const ushort_t* __restrict__ x4, const float* __restrict__ fold,
                  float* __restrict__ out)
{
    int tid  = threadIdx.x;
    int l32  = tid & 31;
    int g    = tid >> 5;
    int R = blockIdx.x * 8 + g;
    int c0 = l32 * 8;
    union { uint4 qv; ushort_t s[8]; } u;
    u.qv = *(const uint4*)(x4 + (size_t)R * 256 + c0);
    float a0 = 0.f, a1 = 0.f;
    #pragma unroll
    for (int j = 0; j < 8; ++j) {
        float v = bf2f(u.s[j]);
        a0 = fmaf(v, fold[(c0 + j) * 2 + 0], a0);
        a1 = fmaf(v, fold[(c0 + j) * 2 + 1], a1);
    }
    #pragma unroll
    for (int off = 16; off > 0; off >>= 1) {
        a0 += __shfl_down(a0, off);
        a1 += __shfl_down(a1, off);
    }
    if (l32 == 0) {
        out[(size_t)R * 2 + 0] = a0 + fold[512];
        out[(size_t)R * 2 + 1] = a1 + fold[513];
    }
}

extern "C" void kernel_launch(void* const* d_in, const int* in_sizes, int n_in,
                              void* d_out, int out_size, void* d_ws, size_t ws_size,
                              hipStream_t stream)
{
    (void)in_sizes; (void)n_in; (void)out_size; (void)ws_size;

    const float* inputs = (const float*)d_in[0];
    const float* m1W1 = (const float*)d_in[3];
    const float* m1b1 = (const float*)d_in[4];
    const float* m1W2 = (const float*)d_in[5];
    const float* m1b2 = (const float*)d_in[6];
    const float* m2W1 = (const float*)d_in[7];
    const float* m2b1 = (const float*)d_in[8];
    const float* m2W2 = (const float*)d_in[9];
    const float* m2b2 = (const float*)d_in[10];
    const float* m3W1 = (const float*)d_in[11];
    const float* m3b1 = (const float*)d_in[12];
    const float* m3W2 = (const float*)d_in[13];
    const float* m3b2 = (const float*)d_in[14];
    const float* m4W1 = (const float*)d_in[15];
    const float* m4b1 = (const float*)d_in[16];
    const float* m4W2 = (const float*)d_in[17];
    const float* m4b2 = (const float*)d_in[18];
    const float* gamma = (const float*)d_in[19];
    const float* beta  = (const float*)d_in[20];
    const float* fcW   = (const float*)d_in[21];
    const float* fcb   = (const float*)d_in[22];
    float* out = (float*)d_out;

    // ---- workspace layout (byte-identical total to known-good R13/R16) ----
    char* ws = (char*)d_ws;
    const size_t BIGB = (size_t)M_BIG * 256 * 2;      // 162,201,600
    const size_t HB   = (size_t)M_SMALL * 256 * 2;    // 1,638,400
    const size_t SM4  = (size_t)M_SMALL * 256 * 4;    // 3,276,800
    ushort_t* bigX     = (ushort_t*)ws;                         // x2 then x4
    ushort_t* pstat    = (ushort_t*)(ws + BIGB);                // 2.53 MB region (2*HB)
    float*    part1    = (float*)(ws + BIGB);                   // aliases pstat (disjoint in time)
    float*    part0    = (float*)(ws + BIGB + 2 * HB);          // SM4 bytes
    ushort_t* Pbuf     = (ushort_t*)(ws + BIGB + 2 * HB + SM4);
    ushort_t* Qbuf     = (ushort_t*)(ws + BIGB + 3 * HB + SM4);
    float*    stats    = (float*)(ws + BIGB + 4 * HB + SM4);
    float*    fold     = stats + 512;
    ushort_t* w1t      = (ushort_t*)(ws + BIGB + 4 * HB + SM4 + 8192);
    ushort_t* w1bt     = w1t  + 256 * 256;
    ushort_t* w2pt     = w1bt + 256 * 256;     // [256][512]
    ushort_t* w2t      = w2pt + 256 * 512;
    ushort_t* w3at     = w2t  + 256 * 256;
    ushort_t* w3bt     = w3at + 256 * 256;
    ushort_t* w4pt     = w3bt + 256 * 256;     // [256][768]
    ushort_t* w4bt     = w4pt + 256 * 768;

    hipMemsetAsync(stats, 0, 2048, stream);
    hipMemsetAsync(part1, 0, SM4, stream);     // continuation slots default 0

    dim3 blk(256);
    dim3 blk512(512);
    wcvt_all<<<176, blk, 0, stream>>>(m1W1, m1W2, m2W1, m2W2, m3W1, m3W2, m4W1, m4W2,
                                      w1t, w1bt, w2pt, w2t, w3at, w3bt, w4pt, w4bt);
    // MLP1 + PQ2 (P/Q halves in parallel, 200 blocks)
    mlp_pq<<<200, blk, 0, stream>>>(inputs, nullptr, 200, 7, 1.f,
                                    w1t, m1b1, w1bt, m1b2,
                                    w2pt, 512, m2b1, Pbuf,
                                    w2pt + 256, Qbuf);
    // edge MLP2 -> x2 + e2n 2-slot partials
    edge_mlp2<<<NBLK2, blk512, 0, stream>>>(Pbuf, Qbuf, w2t, m2b2, bigX, part0, part1);
    // MLP3 + PQ4 (incoming = (part0+part1)/9900; P/Q halves, 200 blocks)
    mlp_pq<<<200, blk, 0, stream>>>(part0, part1, 256, 8, 1.f / 9900.f,
                                    w3at, m3b1, w3bt, m3b2,
                                    w4pt, 768, m4b1, Pbuf,
                                    w4pt + 256, Qbuf);
    // edge MLP4 (skip weight = w4pt cols 512.., stride 768)
    edge_mlp4<<<NBLK2, blk512, 0, stream>>>(Pbuf, Qbuf, bigX,
                                            w4pt + 512, 768, w4bt, 256,
                                            m4b2, bigX, pstat);
    reduce_stats<<<64, blk, 0, stream>>>(pstat, stats);
    fold_kernel<<<1, blk, 0, stream>>>(stats, gamma, beta, fcW, fcb, fold);
    final_kernel<<<M_BIG / 8, blk, 0, stream>>>(bigX, fold, out);
}